// Round 4
// baseline (94.560 us; speedup 1.0000x reference)
//
#include <hip/hip_runtime.h>

// CRPS loss: preds [B=8, N=16, C=4, H=128, W=256] f32, gt [8,4,128,256] f32 -> scalar f32
// out = mean_over_points( sum_n |p_n - g|/N  -  sum_{i<j} |p_i - p_j| / (N*(N-1)) )
//
// Two-kernel deterministic reduction (R2 showed 1024 same-address device atomics
// cost +8us -> never fuse via atomics).
// R4: term2 via sort-then-weighted-sum identity:
//   sum_{i<j} |p_i - p_j| = sum_k (2k-N+1) * p_(k)   (p sorted ascending)
// Batcher odd-even mergesort network (63 CAS, compile-time generated) cuts term2
// from 240 to ~142 VALU instrs per component (~35% total VALU reduction).

#define CHW      131072            // C*H*W = 4*128*256
#define CHW4     32768             // CHW/4 (float4 units)
#define NENS     16
#define BATCH    8
#define NPOINTS  (BATCH * CHW)     // 1,048,576 spatial points
#define NP4      (NPOINTS / 4)     // 262,144 float4 points
#define BLOCK    256
#define GRID1    (NP4 / BLOCK)     // 1024 blocks

// ---- Batcher odd-even mergesort network for n=16, generated at compile time
// from the canonical iterative recurrence (provably correct; 63 comparators).
struct Net { int a[64]; int b[64]; int cnt; };
constexpr Net make_net() {
    Net nt{}; int c = 0; const int n = NENS;
    for (int p = 1; p < n; p <<= 1)
        for (int k = p; k >= 1; k >>= 1)
            for (int j = k % p; j + k < n; j += 2 * k)
                for (int i = 0; i < k && i + j + k < n; ++i)
                    if ((i + j) / (2 * p) == (i + j + k) / (2 * p)) {
                        nt.a[c] = i + j; nt.b[c] = i + j + k; ++c;
                    }
    nt.cnt = c;
    return nt;
}
constexpr Net NET = make_net();
static_assert(make_net().cnt == 63, "Batcher n=16 must have 63 comparators");

__device__ __forceinline__ float4 f4min(float4 u, float4 v) {
    return make_float4(fminf(u.x, v.x), fminf(u.y, v.y), fminf(u.z, v.z), fminf(u.w, v.w));
}
__device__ __forceinline__ float4 f4max(float4 u, float4 v) {
    return make_float4(fmaxf(u.x, v.x), fmaxf(u.y, v.y), fmaxf(u.z, v.z), fmaxf(u.w, v.w));
}

__global__ __launch_bounds__(BLOCK) void crps_partial_kernel(
    const float4* __restrict__ preds,   // [B, N, CHW/4] in float4 units
    const float4* __restrict__ gt,      // [B, CHW/4]
    float* __restrict__ partial)        // [GRID1]
{
    const int t  = blockIdx.x * BLOCK + threadIdx.x;  // float4 point id over [B, CHW/4]
    const int b  = t >> 15;                            // / CHW4
    const int s4 = t & (CHW4 - 1);

    const float4* pbase = preds + ((b * NENS) << 15) + s4;
    const float4 g = gt[t];

    float4 p[NENS];
#pragma unroll
    for (int n = 0; n < NENS; ++n)
        p[n] = pbase[n << 15];   // stride CHW4 float4 between ensemble members

    // term1: sum_i |p_i - g|  (4 independent chains via float4 components)
    float4 t1 = make_float4(0.f, 0.f, 0.f, 0.f);
#pragma unroll
    for (int i = 0; i < NENS; ++i) {
        t1.x += fabsf(p[i].x - g.x);
        t1.y += fabsf(p[i].y - g.y);
        t1.z += fabsf(p[i].z - g.z);
        t1.w += fabsf(p[i].w - g.w);
    }

    // sort the 16 ensemble values per component (Batcher network, 63 CAS)
#pragma unroll
    for (int c = 0; c < 63; ++c) {
        const int ia = NET.a[c], ib = NET.b[c];
        const float4 lo = f4min(p[ia], p[ib]);
        const float4 hi = f4max(p[ia], p[ib]);
        p[ia] = lo; p[ib] = hi;
    }

    // term2: sum_{i<j}|p_i-p_j| = sum_k (2k-15) * p_(k)
    float4 t2 = make_float4(0.f, 0.f, 0.f, 0.f);
#pragma unroll
    for (int k = 0; k < NENS; ++k) {
        const float w = (float)(2 * k - 15);
        t2.x = fmaf(w, p[k].x, t2.x);
        t2.y = fmaf(w, p[k].y, t2.y);
        t2.z = fmaf(w, p[k].z, t2.z);
        t2.w = fmaf(w, p[k].w, t2.w);
    }

    float local = (t1.x + t1.y + t1.z + t1.w) * (1.0f / 16.0f)
                - (t2.x + t2.y + t2.z + t2.w) * (1.0f / 240.0f);

    // wave (64-lane) shuffle reduction
#pragma unroll
    for (int off = 32; off > 0; off >>= 1)
        local += __shfl_down(local, off, 64);

    __shared__ float smem[BLOCK / 64];
    const int lane = threadIdx.x & 63;
    const int wid  = threadIdx.x >> 6;
    if (lane == 0) smem[wid] = local;
    __syncthreads();
    if (threadIdx.x == 0) {
        float s = 0.0f;
#pragma unroll
        for (int w = 0; w < BLOCK / 64; ++w) s += smem[w];
        partial[blockIdx.x] = s;
    }
}

__global__ __launch_bounds__(BLOCK) void crps_final_kernel(
    const float* __restrict__ partial, float* __restrict__ out)
{
    float local = 0.0f;
    for (int i = threadIdx.x; i < GRID1; i += BLOCK)
        local += partial[i];
#pragma unroll
    for (int off = 32; off > 0; off >>= 1)
        local += __shfl_down(local, off, 64);

    __shared__ float smem[BLOCK / 64];
    const int lane = threadIdx.x & 63;
    const int wid  = threadIdx.x >> 6;
    if (lane == 0) smem[wid] = local;
    __syncthreads();
    if (threadIdx.x == 0) {
        float s = 0.0f;
#pragma unroll
        for (int w = 0; w < BLOCK / 64; ++w) s += smem[w];
        out[0] = s * (1.0f / (float)NPOINTS);
    }
}

extern "C" void kernel_launch(void* const* d_in, const int* in_sizes, int n_in,
                              void* d_out, int out_size, void* d_ws, size_t ws_size,
                              hipStream_t stream) {
    const float4* preds = (const float4*)d_in[0];
    const float4* gt    = (const float4*)d_in[1];
    float* partial      = (float*)d_ws;     // GRID1 floats = 4 KiB scratch
    float* out          = (float*)d_out;

    crps_partial_kernel<<<GRID1, BLOCK, 0, stream>>>(preds, gt, partial);
    crps_final_kernel<<<1, BLOCK, 0, stream>>>(partial, out);
}